// Round 3
// baseline (2331.104 us; speedup 1.0000x reference)
//
#include <hip/hip_runtime.h>

typedef __attribute__((ext_vector_type(8))) short bf16x8;
typedef __attribute__((ext_vector_type(4))) float f32x4;
typedef __attribute__((ext_vector_type(4))) float f32x4v;
typedef __attribute__((ext_vector_type(4))) unsigned short u16x4;

#define DEVFN __device__ __forceinline__

DEVFN unsigned short f2bf(float f) {
    union { float f; unsigned int u; } x; x.f = f;
    unsigned int r = (x.u + 0x7fffu + ((x.u >> 16) & 1u)) >> 16;
    return (unsigned short)r;
}

DEVFN void gl_lds16(const void* g, void* l) {
    __builtin_amdgcn_global_load_lds(
        (const __attribute__((address_space(1))) void*)g,
        (__attribute__((address_space(3))) void*)l, 16, 0, 0);
}

DEVFN void wgbar() {
    __builtin_amdgcn_sched_barrier(0);
    asm volatile("" ::: "memory");
    __builtin_amdgcn_s_barrier();
    asm volatile("" ::: "memory");
    __builtin_amdgcn_sched_barrier(0);
}
#define WAITVM(n) asm volatile("s_waitcnt vmcnt(" #n ")" ::: "memory")

// ---------------- fp32 -> bf16 convert (vectorized, grid-stride) ----------------
__global__ void cvt_bf16_kernel(const float* __restrict__ in,
                                unsigned short* __restrict__ out, int n4) {
    int i = blockIdx.x * blockDim.x + threadIdx.x;
    int stride = gridDim.x * blockDim.x;
    for (; i < n4; i += stride) {
        f32x4v v = ((const f32x4v*)in)[i];
        u16x4 o;
        o[0] = f2bf(v[0]); o[1] = f2bf(v[1]); o[2] = f2bf(v[2]); o[3] = f2bf(v[3]);
        ((u16x4*)out)[i] = o;
    }
}

// ---------------- transpose + convert: WT[n][k] = bf16(W[k][n]) ----------------
__global__ void transpose_cvt_kernel(const float* __restrict__ W,
                                     unsigned short* __restrict__ WT, int K, int N) {
    __shared__ unsigned short tile[32][33];
    int tid = threadIdx.x;
    int cx = tid & 31, ry = tid >> 5;
    int bk = blockIdx.y * 32, bn = blockIdx.x * 32;
#pragma unroll
    for (int i = 0; i < 4; ++i)
        tile[ry + i * 8][cx] = f2bf(W[(size_t)(bk + ry + i * 8) * N + bn + cx]);
    __syncthreads();
#pragma unroll
    for (int i = 0; i < 4; ++i)
        WT[(size_t)(bn + ry + i * 8) * K + bk + cx] = tile[cx][ry + i * 8];
}

// ---------------- 256x256 GEMM, BK=32, dbuf 64KiB LDS -> 2 blocks/CU ----------
// A row-major bf16 (row stride lda); BT row-major bf16 (N x 1024).
// 8 waves (2Mx4N), per-wave 128x64 output. Per K-tile (32 cols): 2 phases x 16 MFMA.
// Stage A(t+1)+B(t+1) at START of P0 of tile t (issue-to-wait = 2 phases > HBM lat),
// single vmcnt(0) per tile right before the certifying barrier.
// LDS unit layout: [128 pairs][8 chunks][8 elems], chunk ^= (pair&7) (bank-conflict-free).
template <bool OUT_BF16>
__global__ __launch_bounds__(512, 4) void gemm256_kernel(
    const unsigned short* __restrict__ A, const unsigned short* __restrict__ BT,
    const float* __restrict__ bias, void* __restrict__ C,
    int N, int lda, int nbx) {
    constexpr int K = 1024, NT = K / 32;
    __shared__ __align__(16) unsigned short Als[2][8192];
    __shared__ __align__(16) unsigned short Bls[2][8192];

    int tid = threadIdx.x, lane = tid & 63, wave = tid >> 6;
    int wr = wave >> 2, wc = wave & 3;

    // XCD-aware swizzle (nwg % 8 == 0 guaranteed by launch)
    int nwg = gridDim.x, bid = blockIdx.x;
    int swz = (bid & 7) * (nwg >> 3) + (bid >> 3);
    int bx = swz % nbx, by = swz / nbx;
    int row0 = by * 256, col0 = bx * 256;

    // staging: slot s = i*512 + tid, p=s>>3, stored-chunk sc=s&7, j=sc^(p&7),
    // row=2p+(j>>2), col-chunk c=j&3  -> global src offset (elements)
    int gsA0, gsA1, gsB0, gsB1, ldso0, ldso1;
    {
        int s0 = tid, p0 = s0 >> 3, sc0 = s0 & 7, j0 = sc0 ^ (p0 & 7);
        int r0 = 2 * p0 + (j0 >> 2), c0 = j0 & 3;
        int s1 = 512 + tid, p1 = s1 >> 3, sc1 = s1 & 7, j1 = sc1 ^ (p1 & 7);
        int r1 = 2 * p1 + (j1 >> 2), c1 = j1 & 3;
        gsA0 = (row0 + r0) * lda + c0 * 8;
        gsA1 = (row0 + r1) * lda + c1 * 8;
        gsB0 = (col0 + r0) * K + c0 * 8;
        gsB1 = (col0 + r1) * K + c1 * 8;
        ldso0 = wave * 512;            // slots 0*512+wave*64.. (x8 elems)
        ldso1 = 4096 + wave * 512;     // slots 1*512+wave*64..
    }

    auto stageAB = [&](int db, int koff) {
        unsigned short* uA = &Als[db][0];
        unsigned short* uB = &Bls[db][0];
        gl_lds16(A + gsA0 + koff, uA + ldso0);
        gl_lds16(A + gsA1 + koff, uA + ldso1);
        gl_lds16(BT + gsB0 + koff, uB + ldso0);
        gl_lds16(BT + gsB1 + koff, uB + ldso1);
    };

    // fragment read offsets: lane (fr=lane&15, cq=lane>>4) reads row=base+m*16+fr,
    // cols cq*8..+7 of the 32-col k-tile; pair p = row>>1, swizzled chunk:
    int fr = lane & 15, cq = lane >> 4;
    int scA = (((fr & 1) << 2) | cq) ^ ((fr >> 1) & 7);
    int aoff = (wr * 64 + (fr >> 1)) * 64 + scA * 8;   // + m*512
    int boff = (wc * 32 + (fr >> 1)) * 64 + scA * 8;   // + n*512

#define RD_A(DB, M) (*(const bf16x8*)&Als[DB][aoff + (M) * 512])
#define RD_B(DB, N_) (*(const bf16x8*)&Bls[DB][boff + (N_) * 512])

    f32x4 acc[8][4];
#pragma unroll
    for (int m = 0; m < 8; ++m)
#pragma unroll
        for (int n = 0; n < 4; ++n) acc[m][n] = (f32x4){0.f, 0.f, 0.f, 0.f};

    bf16x8 af[4], bf[4];

#define PH_MFMA(MH) do {                                                        \
        __builtin_amdgcn_s_setprio(1);                                          \
        _Pragma("unroll")                                                       \
        for (int m = 0; m < 4; ++m) {                                           \
            _Pragma("unroll")                                                   \
            for (int n = 0; n < 4; ++n)                                         \
                acc[(MH) * 4 + m][n] = __builtin_amdgcn_mfma_f32_16x16x32_bf16( \
                    af[m], bf[n], acc[(MH) * 4 + m][n], 0, 0, 0);               \
        }                                                                       \
        __builtin_amdgcn_s_setprio(0);                                          \
    } while (0)

    // Per tile t (CUR=t&1, NXT=CUR^1):
    //  P0: stage A(t+1)+B(t+1) -> NXT (issued first), read ks frags m0-3 + n0-3
    //      of CUR, bar, 16 MFMA, bar
    //  P1: read frags m4-7 of CUR, vmcnt(0) (2 phases after issue -> ~no stall),
    //      bar (certifies NXT for all waves), 16 MFMA, bar
#define DO_TILE(T, CUR, NXT) do {                                               \
        const int t_ = (T);                                                     \
        if (t_ + 1 < NT) stageAB(NXT, (t_ + 1) * 32);                           \
        _Pragma("unroll") for (int m = 0; m < 4; ++m) af[m] = RD_A(CUR, m);     \
        _Pragma("unroll") for (int n = 0; n < 4; ++n) bf[n] = RD_B(CUR, n);     \
        wgbar();                                                                \
        PH_MFMA(0);                                                             \
        wgbar();                                                                \
        _Pragma("unroll") for (int m = 0; m < 4; ++m) af[m] = RD_A(CUR, 4 + m); \
        WAITVM(0);                                                              \
        wgbar();                                                                \
        PH_MFMA(1);                                                             \
        wgbar();                                                                \
    } while (0)

    // prologue: tile 0
    stageAB(0, 0);
    WAITVM(0);
    wgbar();

    for (int t = 0; t < NT; t += 2) {
        DO_TILE(t, 0, 1);
        DO_TILE(t + 1, 1, 0);
    }

    // epilogue: C/D layout col = fr, row = cq*4 + j
#pragma unroll
    for (int m = 0; m < 8; ++m) {
        int row = row0 + wr * 128 + m * 16 + cq * 4;
#pragma unroll
        for (int n = 0; n < 4; ++n) {
            int col = col0 + wc * 64 + n * 16 + fr;
            float bsv = bias[col];
#pragma unroll
            for (int j = 0; j < 4; ++j) {
                float v = acc[m][n][j] + bsv;
                if (OUT_BF16)
                    ((unsigned short*)C)[(size_t)(row + j) * N + col] = f2bf(v);
                else
                    ((float*)C)[(size_t)(row + j) * N + col] = v;
            }
        }
    }
#undef RD_A
#undef RD_B
#undef PH_MFMA
#undef DO_TILE
}

// ---------------- per-token cross-head attention ----------------
// qkv[t][0:1024]=q, [1024:2048]=k, [2048:3072]=v  (bf16, head h at h*64)
// writes attention output IN-PLACE into the q region: qkv[t][h*64+d]
__global__ __launch_bounds__(256) void attn_kernel(unsigned short* qkv) {
    __shared__ __align__(16) unsigned short sQ[4][1024];
    __shared__ __align__(16) unsigned short sK[4][1024];
    __shared__ __align__(16) unsigned short sVT[4][1024];  // vT[d][g], 64x16
    int tid = threadIdx.x;
    int lane = tid & 63, wave = tid >> 6;
    int t = blockIdx.x * 4 + wave;
    unsigned short* base = qkv + (size_t)t * 3072;

    gl_lds16(base + lane * 8, &sQ[wave][0]);
    gl_lds16(base + 512 + lane * 8, &sQ[wave][512]);
    gl_lds16(base + 1024 + lane * 8, &sK[wave][0]);
    gl_lds16(base + 1536 + lane * 8, &sK[wave][512]);
    bf16x8 v0 = *(const bf16x8*)(base + 2048 + lane * 8);
    bf16x8 v1 = *(const bf16x8*)(base + 2560 + lane * 8);
    int g0 = lane >> 3, d0 = (lane & 7) * 8;
#pragma unroll
    for (int j = 0; j < 8; ++j) {
        sVT[wave][(d0 + j) * 16 + g0] = (unsigned short)v0[j];
        sVT[wave][(d0 + j) * 16 + g0 + 8] = (unsigned short)v1[j];
    }
    __syncthreads();

    int fr = lane & 15, G = lane >> 4;
    int fo = G * 8;
    bf16x8 ka0 = *(const bf16x8*)(&sK[wave][fr * 64 + fo]);
    bf16x8 qa0 = *(const bf16x8*)(&sQ[wave][fr * 64 + fo]);
    bf16x8 ka1 = *(const bf16x8*)(&sK[wave][fr * 64 + 32 + fo]);
    bf16x8 qa1 = *(const bf16x8*)(&sQ[wave][fr * 64 + 32 + fo]);
    f32x4 s = {0.f, 0.f, 0.f, 0.f};
    s = __builtin_amdgcn_mfma_f32_16x16x32_bf16(ka0, qa0, s, 0, 0, 0);
    s = __builtin_amdgcn_mfma_f32_16x16x32_bf16(ka1, qa1, s, 0, 0, 0);
    float sv[4];
#pragma unroll
    for (int j = 0; j < 4; ++j) sv[j] = s[j] * 0.125f;
    float mx = fmaxf(fmaxf(sv[0], sv[1]), fmaxf(sv[2], sv[3]));
    mx = fmaxf(mx, __shfl_xor(mx, 16));
    mx = fmaxf(mx, __shfl_xor(mx, 32));
    float p[4], sum = 0.f;
#pragma unroll
    for (int j = 0; j < 4; ++j) { p[j] = __expf(sv[j] - mx); sum += p[j]; }
    sum += __shfl_xor(sum, 16);
    sum += __shfl_xor(sum, 32);
    float rinv = 1.0f / sum;

    unsigned int P01 = (unsigned int)f2bf(p[0] * rinv) | ((unsigned int)f2bf(p[1] * rinv) << 16);
    unsigned int P23 = (unsigned int)f2bf(p[2] * rinv) | ((unsigned int)f2bf(p[3] * rinv) << 16);
    int s1 = fr + 32 * (G & 1);
    unsigned int q1a = (unsigned int)__shfl((int)P01, s1);
    unsigned int q1b = (unsigned int)__shfl((int)P23, s1);
    unsigned int q2a = (unsigned int)__shfl((int)P01, s1 + 16);
    unsigned int q2b = (unsigned int)__shfl((int)P23, s1 + 16);
    union { unsigned int u[4]; bf16x8 v; } pu;
    pu.u[0] = q1a; pu.u[1] = q1b; pu.u[2] = q2a; pu.u[3] = q2b;
    bf16x8 pf = {0, 0, 0, 0, 0, 0, 0, 0};
    if (G < 2) pf = pu.v;

    size_t outb = (size_t)t * 3072 + (size_t)fr * 64;
#pragma unroll
    for (int c = 0; c < 4; ++c) {
        bf16x8 vf = {0, 0, 0, 0, 0, 0, 0, 0};
        if (G < 2) vf = *(const bf16x8*)(&sVT[wave][(c * 16 + fr) * 16 + fo]);
        f32x4 o = {0.f, 0.f, 0.f, 0.f};
        o = __builtin_amdgcn_mfma_f32_16x16x32_bf16(vf, pf, o, 0, 0, 0);
        int dd = c * 16 + G * 4;
        u16x4 ov;
#pragma unroll
        for (int j = 0; j < 4; ++j) ov[j] = f2bf(o[j]);
        *(u16x4*)(qkv + outb + dd) = ov;
    }
}

extern "C" void kernel_launch(void* const* d_in, const int* in_sizes, int n_in,
                              void* d_out, int out_size, void* d_ws, size_t ws_size,
                              hipStream_t stream) {
    const float* x  = (const float*)d_in[0];   // 32*1024*1024
    const float* wb = (const float*)d_in[1];   // 1024*3072
    const float* bb = (const float*)d_in[2];   // 3072
    const float* wt = (const float*)d_in[3];   // 1024*1024
    const float* bt = (const float*)d_in[4];   // 1024
    float* out = (float*)d_out;

    unsigned short* xb  = (unsigned short*)d_ws;          // 33,554,432
    unsigned short* wbT = xb + (size_t)33554432;          //  3,145,728
    unsigned short* wtT = wbT + (size_t)3145728;          //  1,048,576
    unsigned short* qkv = wtT + (size_t)1048576;          // 100,663,296

    cvt_bf16_kernel<<<2048, 256, 0, stream>>>(x, xb, 33554432 / 4);
    transpose_cvt_kernel<<<dim3(96, 32), 256, 0, stream>>>(wb, wbT, 1024, 3072);
    transpose_cvt_kernel<<<dim3(32, 32), 256, 0, stream>>>(wt, wtT, 1024, 1024);

    // GEMM1: qkv = x * w_bottom + b_bottom   (M=32768, N=3072) -> 128x12 = 1536 blocks
    gemm256_kernel<true><<<1536, 512, 0, stream>>>(xb, wbT, bb, qkv, 3072, 1024, 12);
    // per-token attention, in-place into q region of qkv
    attn_kernel<<<8192, 256, 0, stream>>>(qkv);
    // GEMM2: out = att * w_top + b_top       (M=32768, N=1024) -> 128x4 = 512 blocks
    gemm256_kernel<false><<<512, 512, 0, stream>>>(qkv, wtT, bt, out, 1024, 3072, 4);
}

// Round 4
// 393.103 us; speedup vs baseline: 5.9300x; 5.9300x over previous
//
#include <hip/hip_runtime.h>

typedef __attribute__((ext_vector_type(8))) short bf16x8;
typedef __attribute__((ext_vector_type(4))) float f32x4;
typedef __attribute__((ext_vector_type(4))) float f32x4v;
typedef __attribute__((ext_vector_type(4))) unsigned short u16x4;

#define DEVFN __device__ __forceinline__

DEVFN unsigned short f2bf(float f) {
    union { float f; unsigned int u; } x; x.f = f;
    unsigned int r = (x.u + 0x7fffu + ((x.u >> 16) & 1u)) >> 16;
    return (unsigned short)r;
}

DEVFN void gl_lds16(const void* g, void* l) {
    __builtin_amdgcn_global_load_lds(
        (const __attribute__((address_space(1))) void*)g,
        (__attribute__((address_space(3))) void*)l, 16, 0, 0);
}

// Barrier with compiler-level memory fence ONLY (no sched_barrier pinning):
// memory ops (ds_read / gl_lds) cannot cross, but the scheduler is free to
// interleave within regions and move register-only MFMAs for overlap.
DEVFN void wgbar() {
    asm volatile("" ::: "memory");
    __builtin_amdgcn_s_barrier();
    asm volatile("" ::: "memory");
}
#define WAITVM(n) asm volatile("s_waitcnt vmcnt(" #n ")" ::: "memory")

// ---------------- fp32 -> bf16 convert (vectorized, grid-stride) ----------------
__global__ void cvt_bf16_kernel(const float* __restrict__ in,
                                unsigned short* __restrict__ out, int n4) {
    int i = blockIdx.x * blockDim.x + threadIdx.x;
    int stride = gridDim.x * blockDim.x;
    for (; i < n4; i += stride) {
        f32x4v v = ((const f32x4v*)in)[i];
        u16x4 o;
        o[0] = f2bf(v[0]); o[1] = f2bf(v[1]); o[2] = f2bf(v[2]); o[3] = f2bf(v[3]);
        ((u16x4*)out)[i] = o;
    }
}

// ---------------- transpose + convert: WT[n][k] = bf16(W[k][n]) ----------------
__global__ void transpose_cvt_kernel(const float* __restrict__ W,
                                     unsigned short* __restrict__ WT, int K, int N) {
    __shared__ unsigned short tile[32][33];
    int tid = threadIdx.x;
    int cx = tid & 31, ry = tid >> 5;
    int bk = blockIdx.y * 32, bn = blockIdx.x * 32;
#pragma unroll
    for (int i = 0; i < 4; ++i)
        tile[ry + i * 8][cx] = f2bf(W[(size_t)(bk + ry + i * 8) * N + bn + cx]);
    __syncthreads();
#pragma unroll
    for (int i = 0; i < 4; ++i)
        WT[(size_t)(bn + ry + i * 8) * K + bk + cx] = tile[cx][ry + i * 8];
}

// ---------------- 256x256 8-phase GEMM: C[M,N] = A[M,K=1024]*BT[N,K]^T + bias --
// A row-major bf16 (row stride lda); BT row-major bf16 (N x 1024).
// 8 waves (2Mx4N), per-wave 128x64 output, BK=64 in 2 k-steps of 32.
// LDS: per matrix [2 dbuf][2 ks][128 pairs][8 chunks][8 elems] bf16, chunk^=(p&7).
// 1 block/CU (register-forced: ~256 regs/wave). Do NOT raise min-waves: a
// (512,4) bound spills acc to scratch (5.3 GB of HBM traffic, 7x slower).
template <bool OUT_BF16>
__global__ __launch_bounds__(512, 2) void gemm256_kernel(
    const unsigned short* __restrict__ A, const unsigned short* __restrict__ BT,
    const float* __restrict__ bias, void* __restrict__ C,
    int N, int lda, int nbx) {
    constexpr int K = 1024, NT = K / 64;
    __shared__ __align__(16) unsigned short Als[2][2][8192];
    __shared__ __align__(16) unsigned short Bls[2][2][8192];

    int tid = threadIdx.x, lane = tid & 63, wave = tid >> 6;
    int wr = wave >> 2, wc = wave & 3;

    // XCD-aware swizzle (nwg % 8 == 0 guaranteed by launch)
    int nwg = gridDim.x, bid = blockIdx.x;
    int swz = (bid & 7) * (nwg >> 3) + (bid >> 3);
    int bx = swz % nbx, by = swz / nbx;
    int row0 = by * 256, col0 = bx * 256;

    // staging: slot s = i*512 + tid, p=s>>3, stored-chunk sc=s&7, j=sc^(p&7),
    // row=2p+(j>>2), col-chunk c=j&3  -> global src offset (elements)
    int gsA0, gsA1, gsB0, gsB1, ldso0, ldso1;
    {
        int s0 = tid, p0 = s0 >> 3, sc0 = s0 & 7, j0 = sc0 ^ (p0 & 7);
        int r0 = 2 * p0 + (j0 >> 2), c0 = j0 & 3;
        int s1 = 512 + tid, p1 = s1 >> 3, sc1 = s1 & 7, j1 = sc1 ^ (p1 & 7);
        int r1 = 2 * p1 + (j1 >> 2), c1 = j1 & 3;
        gsA0 = (row0 + r0) * lda + c0 * 8;
        gsA1 = (row0 + r1) * lda + c1 * 8;
        gsB0 = (col0 + r0) * K + c0 * 8;
        gsB1 = (col0 + r1) * K + c1 * 8;
        ldso0 = wave * 512;            // (0*512 + wave*64) slots * 8 elems
        ldso1 = 4096 + wave * 512;     // (1*512 + wave*64) slots * 8 elems
    }

    auto stageA = [&](int db, int ks, int koff) {
        unsigned short* u = &Als[db][ks][0];
        gl_lds16(A + gsA0 + koff, u + ldso0);
        gl_lds16(A + gsA1 + koff, u + ldso1);
    };
    auto stageB = [&](int db, int ks, int koff) {
        unsigned short* u = &Bls[db][ks][0];
        gl_lds16(BT + gsB0 + koff, u + ldso0);
        gl_lds16(BT + gsB1 + koff, u + ldso1);
    };

    // fragment read offsets: lane (fr=lane&15, cq=lane>>4) reads row=base+m*16+fr,
    // cols cq*8..+7 of a 32-col k-step; pair p, swizzled chunk:
    int fr = lane & 15, cq = lane >> 4;
    int scA = (((fr & 1) << 2) | cq) ^ ((fr >> 1) & 7);
    int aoff = (wr * 64 + (fr >> 1)) * 64 + scA * 8;   // + m*512
    int boff = (wc * 32 + (fr >> 1)) * 64 + scA * 8;   // + n*512

#define RD_A(DB, KS, M) (*(const bf16x8*)&Als[DB][KS][aoff + (M) * 512])
#define RD_B(DB, KS, N_) (*(const bf16x8*)&Bls[DB][KS][boff + (N_) * 512])

    f32x4 acc[8][4];
#pragma unroll
    for (int m = 0; m < 8; ++m)
#pragma unroll
        for (int n = 0; n < 4; ++n) acc[m][n] = (f32x4){0.f, 0.f, 0.f, 0.f};

    bf16x8 af[4], bf[4];

#define PH_MFMA(MH) do {                                                        \
        __builtin_amdgcn_s_setprio(1);                                          \
        _Pragma("unroll")                                                       \
        for (int m = 0; m < 4; ++m) {                                           \
            _Pragma("unroll")                                                   \
            for (int n = 0; n < 4; ++n)                                         \
                acc[(MH) * 4 + m][n] = __builtin_amdgcn_mfma_f32_16x16x32_bf16( \
                    af[m], bf[n], acc[(MH) * 4 + m][n], 0, 0, 0);               \
        }                                                                       \
        __builtin_amdgcn_s_setprio(0);                                          \
    } while (0)

    // Staging order (units of 16KB, 2 gl_lds each), consumed 4+ units later:
    //   prologue: Aks0(0) Bks0(0) Aks1(0) Bks1(0) Aks0(1) Bks0(1)
    //   tile t:   P0: Aks1(t+1)  P1: Bks1(t+1)  P2: Aks0(t+2)  P3: Bks0(t+2)
    // vmcnt(8) = "all but newest 4 units landed" certifies exactly the unit
    // needed 2 phases later (FIFO vmcnt semantics). Never 0 in steady state.
#define DO_TILE(T, CUR, NXT) do {                                               \
        const int t_ = (T);                                                     \
        /* P0: ks0, m0-3 */                                                     \
        _Pragma("unroll") for (int m = 0; m < 4; ++m) af[m] = RD_A(CUR, 0, m);  \
        _Pragma("unroll") for (int n = 0; n < 4; ++n) bf[n] = RD_B(CUR, 0, n);  \
        if (t_ + 1 < NT) stageA(NXT, 1, (t_ + 1) * 64 + 32);                    \
        wgbar();                                                                \
        PH_MFMA(0);                                                             \
        wgbar();                                                                \
        /* P1: ks0, m4-7 (reuse bf) */                                          \
        _Pragma("unroll") for (int m = 0; m < 4; ++m) af[m] = RD_A(CUR, 0, 4 + m); \
        if (t_ + 1 < NT) { stageB(NXT, 1, (t_ + 1) * 64 + 32); WAITVM(8); }     \
        else { WAITVM(0); }                                                     \
        wgbar();                                                                \
        PH_MFMA(1);                                                             \
        wgbar();                                                                \
        /* P2: ks1, m0-3 */                                                     \
        _Pragma("unroll") for (int m = 0; m < 4; ++m) af[m] = RD_A(CUR, 1, m);  \
        _Pragma("unroll") for (int n = 0; n < 4; ++n) bf[n] = RD_B(CUR, 1, n);  \
        if (t_ + 2 < NT) stageA(CUR, 0, (t_ + 2) * 64);                         \
        wgbar();                                                                \
        PH_MFMA(0);                                                             \
        wgbar();                                                                \
        /* P3: ks1, m4-7 */                                                     \
        _Pragma("unroll") for (int m = 0; m < 4; ++m) af[m] = RD_A(CUR, 1, 4 + m); \
        if (t_ + 2 < NT) { stageB(CUR, 0, (t_ + 2) * 64); WAITVM(8); }          \
        else if (t_ + 1 < NT) { WAITVM(4); }                                    \
        wgbar();                                                                \
        PH_MFMA(1);                                                             \
        wgbar();                                                                \
    } while (0)

    // prologue: tile0 fully + tile1 ks0
    stageA(0, 0, 0); stageB(0, 0, 0);
    stageA(0, 1, 32); stageB(0, 1, 32);
    stageA(1, 0, 64); stageB(1, 0, 64);
    WAITVM(8);
    wgbar();

    for (int t = 0; t < NT; t += 2) {
        DO_TILE(t, 0, 1);
        DO_TILE(t + 1, 1, 0);
    }

    // epilogue: C/D layout col = fr, row = cq*4 + j
#pragma unroll
    for (int m = 0; m < 8; ++m) {
        int row = row0 + wr * 128 + m * 16 + cq * 4;
#pragma unroll
        for (int n = 0; n < 4; ++n) {
            int col = col0 + wc * 64 + n * 16 + fr;
            float bsv = bias[col];
#pragma unroll
            for (int j = 0; j < 4; ++j) {
                float v = acc[m][n][j] + bsv;
                if (OUT_BF16)
                    ((unsigned short*)C)[(size_t)(row + j) * N + col] = f2bf(v);
                else
                    ((float*)C)[(size_t)(row + j) * N + col] = v;
            }
        }
    }
#undef RD_A
#undef RD_B
#undef PH_MFMA
#undef DO_TILE
}

// ---------------- per-token cross-head attention ----------------
// qkv[t][0:1024]=q, [1024:2048]=k, [2048:3072]=v  (bf16, head h at h*64)
// writes attention output IN-PLACE into the q region: qkv[t][h*64+d]
__global__ __launch_bounds__(256) void attn_kernel(unsigned short* qkv) {
    __shared__ __align__(16) unsigned short sQ[4][1024];
    __shared__ __align__(16) unsigned short sK[4][1024];
    __shared__ __align__(16) unsigned short sVT[4][1024];  // vT[d][g], 64x16
    int tid = threadIdx.x;
    int lane = tid & 63, wave = tid >> 6;
    int t = blockIdx.x * 4 + wave;
    unsigned short* base = qkv + (size_t)t * 3072;

    gl_lds16(base + lane * 8, &sQ[wave][0]);
    gl_lds16(base + 512 + lane * 8, &sQ[wave][512]);
    gl_lds16(base + 1024 + lane * 8, &sK[wave][0]);
    gl_lds16(base + 1536 + lane * 8, &sK[wave][512]);
    bf16x8 v0 = *(const bf16x8*)(base + 2048 + lane * 8);
    bf16x8 v1 = *(const bf16x8*)(base + 2560 + lane * 8);
    int g0 = lane >> 3, d0 = (lane & 7) * 8;
#pragma unroll
    for (int j = 0; j < 8; ++j) {
        sVT[wave][(d0 + j) * 16 + g0] = (unsigned short)v0[j];
        sVT[wave][(d0 + j) * 16 + g0 + 8] = (unsigned short)v1[j];
    }
    __syncthreads();

    int fr = lane & 15, G = lane >> 4;
    int fo = G * 8;
    bf16x8 ka0 = *(const bf16x8*)(&sK[wave][fr * 64 + fo]);
    bf16x8 qa0 = *(const bf16x8*)(&sQ[wave][fr * 64 + fo]);
    bf16x8 ka1 = *(const bf16x8*)(&sK[wave][fr * 64 + 32 + fo]);
    bf16x8 qa1 = *(const bf16x8*)(&sQ[wave][fr * 64 + 32 + fo]);
    f32x4 s = {0.f, 0.f, 0.f, 0.f};
    s = __builtin_amdgcn_mfma_f32_16x16x32_bf16(ka0, qa0, s, 0, 0, 0);
    s = __builtin_amdgcn_mfma_f32_16x16x32_bf16(ka1, qa1, s, 0, 0, 0);
    float sv[4];
#pragma unroll
    for (int j = 0; j < 4; ++j) sv[j] = s[j] * 0.125f;
    float mx = fmaxf(fmaxf(sv[0], sv[1]), fmaxf(sv[2], sv[3]));
    mx = fmaxf(mx, __shfl_xor(mx, 16));
    mx = fmaxf(mx, __shfl_xor(mx, 32));
    float p[4], sum = 0.f;
#pragma unroll
    for (int j = 0; j < 4; ++j) { p[j] = __expf(sv[j] - mx); sum += p[j]; }
    sum += __shfl_xor(sum, 16);
    sum += __shfl_xor(sum, 32);
    float rinv = 1.0f / sum;

    unsigned int P01 = (unsigned int)f2bf(p[0] * rinv) | ((unsigned int)f2bf(p[1] * rinv) << 16);
    unsigned int P23 = (unsigned int)f2bf(p[2] * rinv) | ((unsigned int)f2bf(p[3] * rinv) << 16);
    int s1 = fr + 32 * (G & 1);
    unsigned int q1a = (unsigned int)__shfl((int)P01, s1);
    unsigned int q1b = (unsigned int)__shfl((int)P23, s1);
    unsigned int q2a = (unsigned int)__shfl((int)P01, s1 + 16);
    unsigned int q2b = (unsigned int)__shfl((int)P23, s1 + 16);
    union { unsigned int u[4]; bf16x8 v; } pu;
    pu.u[0] = q1a; pu.u[1] = q1b; pu.u[2] = q2a; pu.u[3] = q2b;
    bf16x8 pf = {0, 0, 0, 0, 0, 0, 0, 0};
    if (G < 2) pf = pu.v;

    size_t outb = (size_t)t * 3072 + (size_t)fr * 64;
#pragma unroll
    for (int c = 0; c < 4; ++c) {
        bf16x8 vf = {0, 0, 0, 0, 0, 0, 0, 0};
        if (G < 2) vf = *(const bf16x8*)(&sVT[wave][(c * 16 + fr) * 16 + fo]);
        f32x4 o = {0.f, 0.f, 0.f, 0.f};
        o = __builtin_amdgcn_mfma_f32_16x16x32_bf16(vf, pf, o, 0, 0, 0);
        int dd = c * 16 + G * 4;
        u16x4 ov;
#pragma unroll
        for (int j = 0; j < 4; ++j) ov[j] = f2bf(o[j]);
        *(u16x4*)(qkv + outb + dd) = ov;
    }
}

extern "C" void kernel_launch(void* const* d_in, const int* in_sizes, int n_in,
                              void* d_out, int out_size, void* d_ws, size_t ws_size,
                              hipStream_t stream) {
    const float* x  = (const float*)d_in[0];   // 32*1024*1024
    const float* wb = (const float*)d_in[1];   // 1024*3072
    const float* bb = (const float*)d_in[2];   // 3072
    const float* wt = (const float*)d_in[3];   // 1024*1024
    const float* bt = (const float*)d_in[4];   // 1024
    float* out = (float*)d_out;

    unsigned short* xb  = (unsigned short*)d_ws;          // 33,554,432
    unsigned short* wbT = xb + (size_t)33554432;          //  3,145,728
    unsigned short* wtT = wbT + (size_t)3145728;          //  1,048,576
    unsigned short* qkv = wtT + (size_t)1048576;          // 100,663,296

    cvt_bf16_kernel<<<2048, 256, 0, stream>>>(x, xb, 33554432 / 4);
    transpose_cvt_kernel<<<dim3(96, 32), 256, 0, stream>>>(wb, wbT, 1024, 3072);
    transpose_cvt_kernel<<<dim3(32, 32), 256, 0, stream>>>(wt, wtT, 1024, 1024);

    // GEMM1: qkv = x * w_bottom + b_bottom   (M=32768, N=3072) -> 128x12 = 1536 blocks
    gemm256_kernel<true><<<1536, 512, 0, stream>>>(xb, wbT, bb, qkv, 3072, 1024, 12);
    // per-token attention, in-place into q region of qkv
    attn_kernel<<<8192, 256, 0, stream>>>(qkv);
    // GEMM2: out = att * w_top + b_top       (M=32768, N=1024) -> 128x4 = 512 blocks
    gemm256_kernel<false><<<512, 512, 0, stream>>>(qkv, wtT, bt, out, 1024, 3072, 4);
}

// Round 5
// 387.786 us; speedup vs baseline: 6.0113x; 1.0137x over previous
//
#include <hip/hip_runtime.h>

typedef __attribute__((ext_vector_type(8))) short bf16x8;
typedef __attribute__((ext_vector_type(4))) float f32x4;
typedef __attribute__((ext_vector_type(4))) float f32x4v;
typedef __attribute__((ext_vector_type(4))) unsigned short u16x4;

#define DEVFN __device__ __forceinline__

DEVFN unsigned short f2bf(float f) {
    union { float f; unsigned int u; } x; x.f = f;
    unsigned int r = (x.u + 0x7fffu + ((x.u >> 16) & 1u)) >> 16;
    return (unsigned short)r;
}

DEVFN void gl_lds16(const void* g, void* l) {
    __builtin_amdgcn_global_load_lds(
        (const __attribute__((address_space(1))) void*)g,
        (__attribute__((address_space(3))) void*)l, 16, 0, 0);
}

// Barrier with compiler-level memory fence only (memory ops can't cross;
// register-only MFMA may move, which is safe and desired).
DEVFN void wgbar() {
    asm volatile("" ::: "memory");
    __builtin_amdgcn_s_barrier();
    asm volatile("" ::: "memory");
}
#define WAITVM(n) asm volatile("s_waitcnt vmcnt(" #n ")" ::: "memory")
#define LGKM0 asm volatile("s_waitcnt lgkmcnt(0)" ::: "memory")

// ---------------- fp32 -> bf16 convert (vectorized, grid-stride) ----------------
__global__ void cvt_bf16_kernel(const float* __restrict__ in,
                                unsigned short* __restrict__ out, int n4) {
    int i = blockIdx.x * blockDim.x + threadIdx.x;
    int stride = gridDim.x * blockDim.x;
    for (; i < n4; i += stride) {
        f32x4v v = ((const f32x4v*)in)[i];
        u16x4 o;
        o[0] = f2bf(v[0]); o[1] = f2bf(v[1]); o[2] = f2bf(v[2]); o[3] = f2bf(v[3]);
        ((u16x4*)out)[i] = o;
    }
}

// ---------------- transpose + convert: WT[n][k] = bf16(W[k][n]) ----------------
__global__ void transpose_cvt_kernel(const float* __restrict__ W,
                                     unsigned short* __restrict__ WT, int K, int N) {
    __shared__ unsigned short tile[32][33];
    int tid = threadIdx.x;
    int cx = tid & 31, ry = tid >> 5;
    int bk = blockIdx.y * 32, bn = blockIdx.x * 32;
#pragma unroll
    for (int i = 0; i < 4; ++i)
        tile[ry + i * 8][cx] = f2bf(W[(size_t)(bk + ry + i * 8) * N + bn + cx]);
    __syncthreads();
#pragma unroll
    for (int i = 0; i < 4; ++i)
        WT[(size_t)(bn + ry + i * 8) * K + bk + cx] = tile[cx][ry + i * 8];
}

// ---------------- 256x256 GEMM, 1 barrier/phase: C = A*BT^T + bias -----------
// A row-major bf16 (row stride lda); BT row-major bf16 (N x 1024).
// 8 waves (2Mx4N), per-wave 128x64 output, BK=64 in 2 k-steps of 32.
// LDS: per matrix [2 dbuf][2 ks][128 pairs][8 chunks][8 elems] bf16, chunk^=(p&7).
// Phase = {ds_read frags, stage 1 unit, [vmcnt], lgkmcnt(0), s_barrier, 16 MFMA}.
// MFMA of phase k overlaps the LDS reads of phase k+1 (single-barrier schedule).
// lgkmcnt(0) BEFORE the barrier: all waves' reads retired before any wave can
// issue the gl_lds overwrite of that buffer (WAR). WAITVM(8) at P1/P3 certifies
// the buffers read in the FOLLOWING phases before the publishing barrier (RAW).
// 1 block/CU (register-forced ~256/wave). Do NOT raise min-waves: (512,4)
// spills acc to scratch (5.3 GB HBM traffic, 7x slower — round 3).
template <bool OUT_BF16>
__global__ __launch_bounds__(512, 2) void gemm256_kernel(
    const unsigned short* __restrict__ A, const unsigned short* __restrict__ BT,
    const float* __restrict__ bias, void* __restrict__ C,
    int N, int lda, int nbx) {
    constexpr int K = 1024, NT = K / 64;
    __shared__ __align__(16) unsigned short Als[2][2][8192];
    __shared__ __align__(16) unsigned short Bls[2][2][8192];

    int tid = threadIdx.x, lane = tid & 63, wave = tid >> 6;
    int wr = wave >> 2, wc = wave & 3;

    // XCD-aware swizzle (nwg % 8 == 0 guaranteed by launch)
    int nwg = gridDim.x, bid = blockIdx.x;
    int swz = (bid & 7) * (nwg >> 3) + (bid >> 3);
    int bx = swz % nbx, by = swz / nbx;
    int row0 = by * 256, col0 = bx * 256;

    // staging: slot s = i*512 + tid, p=s>>3, stored-chunk sc=s&7, j=sc^(p&7),
    // row=2p+(j>>2), col-chunk c=j&3  -> global src offset (elements)
    int gsA0, gsA1, gsB0, gsB1, ldso0, ldso1;
    {
        int s0 = tid, p0 = s0 >> 3, sc0 = s0 & 7, j0 = sc0 ^ (p0 & 7);
        int r0 = 2 * p0 + (j0 >> 2), c0 = j0 & 3;
        int s1 = 512 + tid, p1 = s1 >> 3, sc1 = s1 & 7, j1 = sc1 ^ (p1 & 7);
        int r1 = 2 * p1 + (j1 >> 2), c1 = j1 & 3;
        gsA0 = (row0 + r0) * lda + c0 * 8;
        gsA1 = (row0 + r1) * lda + c1 * 8;
        gsB0 = (col0 + r0) * K + c0 * 8;
        gsB1 = (col0 + r1) * K + c1 * 8;
        ldso0 = wave * 512;            // (0*512 + wave*64) slots * 8 elems
        ldso1 = 4096 + wave * 512;     // (1*512 + wave*64) slots * 8 elems
    }

    auto stageA = [&](int db, int ks, int koff) {
        unsigned short* u = &Als[db][ks][0];
        gl_lds16(A + gsA0 + koff, u + ldso0);
        gl_lds16(A + gsA1 + koff, u + ldso1);
    };
    auto stageB = [&](int db, int ks, int koff) {
        unsigned short* u = &Bls[db][ks][0];
        gl_lds16(BT + gsB0 + koff, u + ldso0);
        gl_lds16(BT + gsB1 + koff, u + ldso1);
    };

    // fragment read offsets: lane (fr=lane&15, cq=lane>>4) reads row=base+m*16+fr,
    // cols cq*8..+7 of a 32-col k-step; pair p, swizzled chunk:
    int fr = lane & 15, cq = lane >> 4;
    int scA = (((fr & 1) << 2) | cq) ^ ((fr >> 1) & 7);
    int aoff = (wr * 64 + (fr >> 1)) * 64 + scA * 8;   // + m*512
    int boff = (wc * 32 + (fr >> 1)) * 64 + scA * 8;   // + n*512

#define RD_A(DB, KS, M) (*(const bf16x8*)&Als[DB][KS][aoff + (M) * 512])
#define RD_B(DB, KS, N_) (*(const bf16x8*)&Bls[DB][KS][boff + (N_) * 512])

    f32x4 acc[8][4];
#pragma unroll
    for (int m = 0; m < 8; ++m)
#pragma unroll
        for (int n = 0; n < 4; ++n) acc[m][n] = (f32x4){0.f, 0.f, 0.f, 0.f};

    bf16x8 af[4], bf[4];

#define PH_MFMA(MH) do {                                                        \
        __builtin_amdgcn_s_setprio(1);                                          \
        _Pragma("unroll")                                                       \
        for (int m = 0; m < 4; ++m) {                                           \
            _Pragma("unroll")                                                   \
            for (int n = 0; n < 4; ++n)                                         \
                acc[(MH) * 4 + m][n] = __builtin_amdgcn_mfma_f32_16x16x32_bf16( \
                    af[m], bf[n], acc[(MH) * 4 + m][n], 0, 0, 0);               \
        }                                                                       \
        __builtin_amdgcn_s_setprio(0);                                          \
    } while (0)

    // Staging order (units of 16KB, 2 gl_lds/wave each):
    //   prologue: Aks0(0) Bks0(0) Aks1(0) Bks1(0) Aks0(1) Bks0(1)
    //   tile t:   P0: Aks1(t+1)  P1: Bks1(t+1)  P2: Aks0(t+2)  P3: Bks0(t+2)
    // WAITVM(8) = all but newest 4 units landed (FIFO): at P1 certifies
    // Aks1(t)/Bks1(t) for P2/P3 reads; at P3 certifies Aks0(t+1)/Bks0(t+1)
    // for the next tile's P0/P1 reads. Never 0 in steady state.
#define DO_TILE(T, CUR, NXT) do {                                               \
        const int t_ = (T);                                                     \
        /* P0: ks0, m0-3 */                                                     \
        _Pragma("unroll") for (int m = 0; m < 4; ++m) af[m] = RD_A(CUR, 0, m);  \
        _Pragma("unroll") for (int n = 0; n < 4; ++n) bf[n] = RD_B(CUR, 0, n);  \
        if (t_ + 1 < NT) stageA(NXT, 1, (t_ + 1) * 64 + 32);                    \
        LGKM0;                                                                  \
        wgbar();                                                                \
        PH_MFMA(0);                                                             \
        /* P1: ks0, m4-7 (reuse bf) */                                          \
        _Pragma("unroll") for (int m = 0; m < 4; ++m) af[m] = RD_A(CUR, 0, 4 + m); \
        if (t_ + 1 < NT) { stageB(NXT, 1, (t_ + 1) * 64 + 32); WAITVM(8); }     \
        else { WAITVM(0); }                                                     \
        LGKM0;                                                                  \
        wgbar();                                                                \
        PH_MFMA(1);                                                             \
        /* P2: ks1, m0-3 */                                                     \
        _Pragma("unroll") for (int m = 0; m < 4; ++m) af[m] = RD_A(CUR, 1, m);  \
        _Pragma("unroll") for (int n = 0; n < 4; ++n) bf[n] = RD_B(CUR, 1, n);  \
        if (t_ + 2 < NT) stageA(CUR, 0, (t_ + 2) * 64);                         \
        LGKM0;                                                                  \
        wgbar();                                                                \
        PH_MFMA(0);                                                             \
        /* P3: ks1, m4-7 */                                                     \
        _Pragma("unroll") for (int m = 0; m < 4; ++m) af[m] = RD_A(CUR, 1, 4 + m); \
        if (t_ + 2 < NT) { stageB(CUR, 0, (t_ + 2) * 64); WAITVM(8); }          \
        else if (t_ + 1 < NT) { WAITVM(4); }                                    \
        LGKM0;                                                                  \
        wgbar();                                                                \
        PH_MFMA(1);                                                             \
    } while (0)

    // prologue: tile0 fully + tile1 ks0
    stageA(0, 0, 0); stageB(0, 0, 0);
    stageA(0, 1, 32); stageB(0, 1, 32);
    stageA(1, 0, 64); stageB(1, 0, 64);
    WAITVM(8);
    wgbar();

    for (int t = 0; t < NT; t += 2) {
        DO_TILE(t, 0, 1);
        DO_TILE(t + 1, 1, 0);
    }

    // epilogue: C/D layout col = fr, row = cq*4 + j
#pragma unroll
    for (int m = 0; m < 8; ++m) {
        int row = row0 + wr * 128 + m * 16 + cq * 4;
#pragma unroll
        for (int n = 0; n < 4; ++n) {
            int col = col0 + wc * 64 + n * 16 + fr;
            float bsv = bias[col];
#pragma unroll
            for (int j = 0; j < 4; ++j) {
                float v = acc[m][n][j] + bsv;
                if (OUT_BF16)
                    ((unsigned short*)C)[(size_t)(row + j) * N + col] = f2bf(v);
                else
                    ((float*)C)[(size_t)(row + j) * N + col] = v;
            }
        }
    }
#undef RD_A
#undef RD_B
#undef PH_MFMA
#undef DO_TILE
}

// ---------------- per-token cross-head attention ----------------
// qkv[t][0:1024]=q, [1024:2048]=k, [2048:3072]=v  (bf16, head h at h*64)
// writes attention output IN-PLACE into the q region: qkv[t][h*64+d]
__global__ __launch_bounds__(256) void attn_kernel(unsigned short* qkv) {
    __shared__ __align__(16) unsigned short sQ[4][1024];
    __shared__ __align__(16) unsigned short sK[4][1024];
    __shared__ __align__(16) unsigned short sVT[4][1024];  // vT[d][g], 64x16
    int tid = threadIdx.x;
    int lane = tid & 63, wave = tid >> 6;
    int t = blockIdx.x * 4 + wave;
    unsigned short* base = qkv + (size_t)t * 3072;

    gl_lds16(base + lane * 8, &sQ[wave][0]);
    gl_lds16(base + 512 + lane * 8, &sQ[wave][512]);
    gl_lds16(base + 1024 + lane * 8, &sK[wave][0]);
    gl_lds16(base + 1536 + lane * 8, &sK[wave][512]);
    bf16x8 v0 = *(const bf16x8*)(base + 2048 + lane * 8);
    bf16x8 v1 = *(const bf16x8*)(base + 2560 + lane * 8);
    int g0 = lane >> 3, d0 = (lane & 7) * 8;
#pragma unroll
    for (int j = 0; j < 8; ++j) {
        sVT[wave][(d0 + j) * 16 + g0] = (unsigned short)v0[j];
        sVT[wave][(d0 + j) * 16 + g0 + 8] = (unsigned short)v1[j];
    }
    __syncthreads();

    int fr = lane & 15, G = lane >> 4;
    int fo = G * 8;
    bf16x8 ka0 = *(const bf16x8*)(&sK[wave][fr * 64 + fo]);
    bf16x8 qa0 = *(const bf16x8*)(&sQ[wave][fr * 64 + fo]);
    bf16x8 ka1 = *(const bf16x8*)(&sK[wave][fr * 64 + 32 + fo]);
    bf16x8 qa1 = *(const bf16x8*)(&sQ[wave][fr * 64 + 32 + fo]);
    f32x4 s = {0.f, 0.f, 0.f, 0.f};
    s = __builtin_amdgcn_mfma_f32_16x16x32_bf16(ka0, qa0, s, 0, 0, 0);
    s = __builtin_amdgcn_mfma_f32_16x16x32_bf16(ka1, qa1, s, 0, 0, 0);
    float sv[4];
#pragma unroll
    for (int j = 0; j < 4; ++j) sv[j] = s[j] * 0.125f;
    float mx = fmaxf(fmaxf(sv[0], sv[1]), fmaxf(sv[2], sv[3]));
    mx = fmaxf(mx, __shfl_xor(mx, 16));
    mx = fmaxf(mx, __shfl_xor(mx, 32));
    float p[4], sum = 0.f;
#pragma unroll
    for (int j = 0; j < 4; ++j) { p[j] = __expf(sv[j] - mx); sum += p[j]; }
    sum += __shfl_xor(sum, 16);
    sum += __shfl_xor(sum, 32);
    float rinv = 1.0f / sum;

    unsigned int P01 = (unsigned int)f2bf(p[0] * rinv) | ((unsigned int)f2bf(p[1] * rinv) << 16);
    unsigned int P23 = (unsigned int)f2bf(p[2] * rinv) | ((unsigned int)f2bf(p[3] * rinv) << 16);
    int s1 = fr + 32 * (G & 1);
    unsigned int q1a = (unsigned int)__shfl((int)P01, s1);
    unsigned int q1b = (unsigned int)__shfl((int)P23, s1);
    unsigned int q2a = (unsigned int)__shfl((int)P01, s1 + 16);
    unsigned int q2b = (unsigned int)__shfl((int)P23, s1 + 16);
    union { unsigned int u[4]; bf16x8 v; } pu;
    pu.u[0] = q1a; pu.u[1] = q1b; pu.u[2] = q2a; pu.u[3] = q2b;
    bf16x8 pf = {0, 0, 0, 0, 0, 0, 0, 0};
    if (G < 2) pf = pu.v;

    size_t outb = (size_t)t * 3072 + (size_t)fr * 64;
#pragma unroll
    for (int c = 0; c < 4; ++c) {
        bf16x8 vf = {0, 0, 0, 0, 0, 0, 0, 0};
        if (G < 2) vf = *(const bf16x8*)(&sVT[wave][(c * 16 + fr) * 16 + fo]);
        f32x4 o = {0.f, 0.f, 0.f, 0.f};
        o = __builtin_amdgcn_mfma_f32_16x16x32_bf16(vf, pf, o, 0, 0, 0);
        int dd = c * 16 + G * 4;
        u16x4 ov;
#pragma unroll
        for (int j = 0; j < 4; ++j) ov[j] = f2bf(o[j]);
        *(u16x4*)(qkv + outb + dd) = ov;
    }
}

extern "C" void kernel_launch(void* const* d_in, const int* in_sizes, int n_in,
                              void* d_out, int out_size, void* d_ws, size_t ws_size,
                              hipStream_t stream) {
    const float* x  = (const float*)d_in[0];   // 32*1024*1024
    const float* wb = (const float*)d_in[1];   // 1024*3072
    const float* bb = (const float*)d_in[2];   // 3072
    const float* wt = (const float*)d_in[3];   // 1024*1024
    const float* bt = (const float*)d_in[4];   // 1024
    float* out = (float*)d_out;

    unsigned short* xb  = (unsigned short*)d_ws;          // 33,554,432
    unsigned short* wbT = xb + (size_t)33554432;          //  3,145,728
    unsigned short* wtT = wbT + (size_t)3145728;          //  1,048,576
    unsigned short* qkv = wtT + (size_t)1048576;          // 100,663,296

    cvt_bf16_kernel<<<2048, 256, 0, stream>>>(x, xb, 33554432 / 4);
    transpose_cvt_kernel<<<dim3(96, 32), 256, 0, stream>>>(wb, wbT, 1024, 3072);
    transpose_cvt_kernel<<<dim3(32, 32), 256, 0, stream>>>(wt, wtT, 1024, 1024);

    // GEMM1: qkv = x * w_bottom + b_bottom   (M=32768, N=3072) -> 128x12 = 1536 blocks
    gemm256_kernel<true><<<1536, 512, 0, stream>>>(xb, wbT, bb, qkv, 3072, 1024, 12);
    // per-token attention, in-place into q region of qkv
    attn_kernel<<<8192, 256, 0, stream>>>(qkv);
    // GEMM2: out = att * w_top + b_top       (M=32768, N=1024) -> 128x4 = 512 blocks
    gemm256_kernel<false><<<512, 512, 0, stream>>>(qkv, wtT, bt, out, 1024, 3072, 4);
}